// Round 1
// baseline (1618.142 us; speedup 1.0000x reference)
//
#include <hip/hip_runtime.h>
#include <hip/hip_bf16.h>
#include <stdint.h>

typedef unsigned short u16;

#define IN_F   4096
#define OUT_F  11008
#define M_TOT  8192   /* 4*2048 */

__device__ __constant__ float NF4_TAB[16] = {
    -1.0f, -0.6961928009986877f, -0.5250730514526367f, -0.39491748809814453f,
    -0.28444138169288635f, -0.18477343022823334f, -0.09105003625154495f, 0.0f,
    0.07958029955625534f, 0.16093020141124725f, 0.24611230194568634f,
    0.33791524171829224f, 0.44070982933044434f, 0.5626170039176941f,
    0.7229568362236023f, 1.0f};

static __device__ __forceinline__ unsigned f2bf(float f) {
  unsigned u = __float_as_uint(f);
  u += 0x7fffu + ((u >> 16) & 1u);   // round-to-nearest-even
  return u >> 16;
}

// ---------------- dequant W: codes(int32)+absmax -> bf16, 8 elems/thread ----
__global__ __launch_bounds__(256) void dequant_w_kernel(
    const int* __restrict__ codes, const float* __restrict__ absmax,
    uint4* __restrict__ wout, int n8) {
  __shared__ float lut[16];
  if (threadIdx.x < 16) lut[threadIdx.x] = NF4_TAB[threadIdx.x];
  __syncthreads();
  int t = blockIdx.x * 256 + threadIdx.x;
  if (t >= n8) return;
  const int4* cp = (const int4*)codes + (size_t)t * 2;
  int4 c0 = cp[0];
  int4 c1 = cp[1];
  float am = absmax[t >> 3];          // 8 elems all inside one 64-block
  unsigned h0 = f2bf(lut[c0.x] * am) | (f2bf(lut[c0.y] * am) << 16);
  unsigned h1 = f2bf(lut[c0.z] * am) | (f2bf(lut[c0.w] * am) << 16);
  unsigned h2 = f2bf(lut[c1.x] * am) | (f2bf(lut[c1.y] * am) << 16);
  unsigned h3 = f2bf(lut[c1.z] * am) | (f2bf(lut[c1.w] * am) << 16);
  wout[t] = make_uint4(h0, h1, h2, h3);
}

// ---------------- convert x: fp32 -> bf16, 8 elems/thread -------------------
__global__ __launch_bounds__(256) void convert_x_kernel(
    const float4* __restrict__ x, uint4* __restrict__ xout, int n8) {
  int t = blockIdx.x * 256 + threadIdx.x;
  if (t >= n8) return;
  float4 a = x[(size_t)t * 2];
  float4 b = x[(size_t)t * 2 + 1];
  unsigned h0 = f2bf(a.x) | (f2bf(a.y) << 16);
  unsigned h1 = f2bf(a.z) | (f2bf(a.w) << 16);
  unsigned h2 = f2bf(b.x) | (f2bf(b.y) << 16);
  unsigned h3 = f2bf(b.z) | (f2bf(b.w) << 16);
  xout[t] = make_uint4(h0, h1, h2, h3);
}

// ---------------- bf16 MFMA GEMM (m97 structure): C[M,N] = A[M,K] * B[N,K]^T
typedef __attribute__((ext_vector_type(8))) short short8;
typedef __attribute__((ext_vector_type(4))) float f32x4;

static __device__ __forceinline__ void async_copy16(const u16* g, u16* l) {
  __builtin_amdgcn_global_load_lds(
      (const __attribute__((address_space(1))) unsigned int*)g,
      (__attribute__((address_space(3))) unsigned int*)l, 16, 0, 0);
}

__global__ __launch_bounds__(256) void gemm_bt_bf16_kernel(
    const u16* __restrict__ A,   // [M_TOT, IN_F] bf16 bits
    const u16* __restrict__ B,   // [OUT_F, IN_F] bf16 bits
    float* __restrict__ C) {     // [M_TOT, OUT_F]
  constexpr int K = IN_F;
  constexpr int N = OUT_F;
  __shared__ u16 As[128 * 64];   // 16 KB, unpadded (global_load_lds constraint)
  __shared__ u16 Bs[128 * 64];

  const int tid   = threadIdx.x;
  const int wave  = tid >> 6;
  const int lane  = tid & 63;
  const int m0    = blockIdx.y * 128;
  const int n0    = blockIdx.x * 128;
  const int wm    = (wave >> 1) * 64;   // wave's 64x64 sub-tile
  const int wn    = (wave & 1) * 64;
  const int row16 = lane & 15;
  const int quad  = lane >> 4;
  const int srow  = lane >> 3;          // staging: row within 8-row segment
  const int scol  = (lane & 7) * 8;     // staging: col start (8 bf16 = 16 B)

  f32x4 acc[4][4] = {};

  for (int k0 = 0; k0 < K; k0 += 64) {
#pragma unroll
    for (int j = 0; j < 4; ++j) {
      const int seg = wave * 4 + j;     // 16 segments of 1024 B per tile
      const int r   = seg * 8 + srow;
      async_copy16(A + (size_t)(m0 + r) * K + (k0 + scol), &As[seg * 512]);
      async_copy16(B + (size_t)(n0 + r) * K + (k0 + scol), &Bs[seg * 512]);
    }
    __syncthreads();
#pragma unroll
    for (int kk = 0; kk < 64; kk += 32) {
      short8 af[4], bfr[4];
#pragma unroll
      for (int i = 0; i < 4; ++i)
        af[i] = *(const short8*)&As[(wm + i * 16 + row16) * 64 + kk + quad * 8];
#pragma unroll
      for (int j = 0; j < 4; ++j)
        bfr[j] = *(const short8*)&Bs[(wn + j * 16 + row16) * 64 + kk + quad * 8];
#pragma unroll
      for (int i = 0; i < 4; ++i)
#pragma unroll
        for (int j = 0; j < 4; ++j)
          acc[i][j] = __builtin_amdgcn_mfma_f32_16x16x32_bf16(
              af[i], bfr[j], acc[i][j], 0, 0, 0);
    }
    __syncthreads();
  }

  // Epilogue: C/D layout col = lane&15, row = quad*4 + reg  [m89/m91]
#pragma unroll
  for (int i = 0; i < 4; ++i)
#pragma unroll
    for (int j = 0; j < 4; ++j)
#pragma unroll
      for (int r = 0; r < 4; ++r)
        C[(size_t)(m0 + wm + i * 16 + quad * 4 + r) * N +
          (n0 + wn + j * 16 + row16)] = acc[i][j][r];
}

// ---------------- fallback (ws too small): slow but correct -----------------
__global__ void fallback_kernel(const float* __restrict__ x,
                                const int* __restrict__ codes,
                                const float* __restrict__ absmax,
                                float* __restrict__ out) {
  __shared__ float lut[16];
  __shared__ float xs[16][17];
  __shared__ float ws[16][17];
  const int tx = threadIdx.x, ty = threadIdx.y;
  if (ty == 0 && tx < 16) lut[tx] = NF4_TAB[tx];
  __syncthreads();
  const int m  = blockIdx.y * 16 + ty;
  const int n0 = blockIdx.x * 16;
  float acc = 0.f;
  for (int k0 = 0; k0 < IN_F; k0 += 16) {
    xs[ty][tx] = x[(size_t)m * IN_F + k0 + tx];
    int idx = (n0 + ty) * IN_F + k0 + tx;
    ws[ty][tx] = lut[codes[idx]] * absmax[idx >> 6];
    __syncthreads();
#pragma unroll
    for (int kk = 0; kk < 16; ++kk) acc += xs[ty][kk] * ws[tx][kk];
    __syncthreads();
  }
  out[(size_t)m * OUT_F + n0 + tx] = acc;
}

// ---------------------------------------------------------------------------
extern "C" void kernel_launch(void* const* d_in, const int* in_sizes, int n_in,
                              void* d_out, int out_size, void* d_ws, size_t ws_size,
                              hipStream_t stream) {
  const float* x      = (const float*)d_in[0];  // [4,2048,4096] fp32
  const int*   codes  = (const int*)d_in[1];    // [11008,4096] int32 in [0,16)
  const float* absmax = (const float*)d_in[2];  // [704512] fp32
  float* out = (float*)d_out;                   // [4,2048,11008] fp32

  const size_t wBytes = (size_t)OUT_F * IN_F * 2;  // 90,177,536
  const size_t xBytes = (size_t)M_TOT * IN_F * 2;  // 67,108,864

  if (ws_size >= wBytes + xBytes) {
    u16* wq = (u16*)d_ws;
    u16* xq = (u16*)((char*)d_ws + wBytes);

    const int n8w = OUT_F * IN_F / 8;
    dequant_w_kernel<<<(n8w + 255) / 256, 256, 0, stream>>>(
        codes, absmax, (uint4*)wq, n8w);

    const int n8x = M_TOT * IN_F / 8;
    convert_x_kernel<<<(n8x + 255) / 256, 256, 0, stream>>>(
        (const float4*)x, (uint4*)xq, n8x);

    dim3 grid(OUT_F / 128, M_TOT / 128);  // (86, 64)
    gemm_bt_bf16_kernel<<<grid, 256, 0, stream>>>(xq, wq, out);
  } else {
    dim3 blk(16, 16);
    dim3 grid(OUT_F / 16, M_TOT / 16);    // (688, 512)
    fallback_kernel<<<grid, blk, 0, stream>>>(x, codes, absmax, out);
  }
}